// Round 1
// baseline (627.812 us; speedup 1.0000x reference)
//
#include <hip/hip_runtime.h>

// OHEM loss, MI355X. B=8, C=19, H=512, W=1024.
// Fused single-kernel version:
//  - online-softmax streaming over classes: only ONE class value live at a time
//    (old kernel held 19 float4 = 76 mandatory VGPRs -> spill/serialization risk).
//    Register pressure becomes elastic; compiler pipelines the 19 strided loads.
//  - finalize fused via last-block ticket (one kernel launch instead of two).
// Main path: n_over = count(loss > 0.7) >> MIN_KEPT with this data, so
// kept_sum == sum(loss where loss > 0.7), no sort needed.
// Fallback (n_over < MIN_KEPT) handled in the last block via value bisection.

#define BB 8
#define CC 19
#define HW (512 * 1024)
#define THRESH 0.7f
#define MIN_KEPT 10000
#define QHW (HW / 4)
#define NBLKX (HW / (4 * 256))   // 512 blocks per batch
#define NBLK (NBLKX * BB)        // 4096 total

__device__ __forceinline__ float wave_reduce_f(float v) {
#pragma unroll
    for (int off = 32; off > 0; off >>= 1) v += __shfl_down(v, off, 64);
    return v;
}
__device__ __forceinline__ int wave_reduce_i(int v) {
#pragma unroll
    for (int off = 32; off > 0; off >>= 1) v += __shfl_down(v, off, 64);
    return v;
}

// ---------------- fallback helpers (never triggered with this data) ----------
__device__ float pixel_loss(const float* __restrict__ preds,
                            const int* __restrict__ tgts, int b, int i) {
    const float* p = preds + (size_t)b * CC * HW + i;
    const int t = tgts[(size_t)b * HW + i];
    float m = -1e30f, tv = 0.f;
#pragma unroll
    for (int c = 0; c < CC; ++c) {
        float v = p[(size_t)c * HW];
        m = fmaxf(m, v);
        tv = (c == t) ? v : tv;
    }
    float s = 0.f;
#pragma unroll
    for (int c = 0; c < CC; ++c) s += __expf(p[(size_t)c * HW] - m);
    return m - tv + __logf(s);
}

__device__ int block_reduce_int(int v, int* buf) {
    v = wave_reduce_i(v);
    const int wid = threadIdx.x >> 6, lane = threadIdx.x & 63;
    __syncthreads();
    if (lane == 0) buf[wid] = v;
    __syncthreads();
    return buf[0] + buf[1] + buf[2] + buf[3];
}
__device__ float block_reduce_f(float v, float* buf) {
    v = wave_reduce_f(v);
    const int wid = threadIdx.x >> 6, lane = threadIdx.x & 63;
    __syncthreads();
    if (lane == 0) buf[wid] = v;
    __syncthreads();
    return buf[0] + buf[1] + buf[2] + buf[3];
}

// ---------------- fused loss + finalize ----------------
// grid: (NBLKX, BB), block: 256. Each thread: 4 consecutive pixels (float4).
__global__ __launch_bounds__(256) void ohem_fused(
    const float* __restrict__ preds, const int* __restrict__ tgts,
    float* __restrict__ sums, int* __restrict__ counts,
    unsigned int* __restrict__ ticket, float* __restrict__ out) {
    const int b = blockIdx.y;
    const int q = blockIdx.x * 256 + threadIdx.x;  // quad index within batch

    const float4* p4 = (const float4*)(preds + (size_t)b * CC * HW);
    const int4* t4 = (const int4*)(tgts + (size_t)b * HW);

    const int4 t = t4[q];

    // class 0 initializes the online-softmax state
    float4 v0 = p4[q];
    float4 m = v0;                      // running max
    float4 tv = v0;                     // logit[target] (overwritten when t==c)
    float4 s = {1.f, 1.f, 1.f, 1.f};    // running sum of exp(a - m)

#pragma unroll
    for (int c = 1; c < CC; ++c) {
        const float4 a = p4[(size_t)c * QHW + q];
#define ONLINE(comp)                                                        \
        {                                                                   \
            const float nm = fmaxf(m.comp, a.comp);                         \
            s.comp = s.comp * __expf(m.comp - nm) + __expf(a.comp - nm);    \
            m.comp = nm;                                                    \
            tv.comp = (t.comp == c) ? a.comp : tv.comp;                     \
        }
        ONLINE(x) ONLINE(y) ONLINE(z) ONLINE(w)
#undef ONLINE
    }

    const float l0 = m.x - tv.x + __logf(s.x);
    const float l1 = m.y - tv.y + __logf(s.y);
    const float l2 = m.z - tv.z + __logf(s.z);
    const float l3 = m.w - tv.w + __logf(s.w);

    float sloc = 0.f;
    int cloc = 0;
    if (l0 > THRESH) { sloc += l0; ++cloc; }
    if (l1 > THRESH) { sloc += l1; ++cloc; }
    if (l2 > THRESH) { sloc += l2; ++cloc; }
    if (l3 > THRESH) { sloc += l3; ++cloc; }

    // block reduce: 4 waves
    __shared__ float sbuf[4];
    __shared__ int cbuf[4];
    __shared__ int lastflag;
    const float wsum = wave_reduce_f(sloc);
    const int wcnt = wave_reduce_i(cloc);
    const int wid = threadIdx.x >> 6;
    const int lane = threadIdx.x & 63;
    if (threadIdx.x == 0) lastflag = 0;
    if (lane == 0) { sbuf[wid] = wsum; cbuf[wid] = wcnt; }
    __syncthreads();
    if (threadIdx.x == 0) {
        const float st = sbuf[0] + sbuf[1] + sbuf[2] + sbuf[3];
        const int ct = cbuf[0] + cbuf[1] + cbuf[2] + cbuf[3];
        atomicAdd(&sums[b], st);
        atomicAdd(&counts[b], ct);
        __threadfence();  // make our adds visible before taking a ticket
        const unsigned int old = atomicAdd(ticket, 1u);
        if (old == (unsigned int)(NBLK - 1)) lastflag = 1;
    }
    __syncthreads();
    if (!lastflag) return;

    // ---- last block: finalize (all other blocks' adds are ordered before us
    // via their threadfence + the ticket atomic chain) ----
    __shared__ int ibuf[4];
    __shared__ float fbuf[4];
    __shared__ float s_sm;
    __shared__ int s_ct;

    float total = 0.f;
    for (int bb = 0; bb < BB; ++bb) {
        if (threadIdx.x == 0) {
            // device-scope atomic reads (avoid any stale L1/L2 copy)
            s_sm = atomicAdd(&sums[bb], 0.0f);
            s_ct = atomicAdd(&counts[bb], 0);
        }
        __syncthreads();
        const int cnt = s_ct;
        const float sm = s_sm;
        float mean;
        if (cnt >= MIN_KEPT) {
            // top-n_over == exactly the losses > THRESH
            mean = sm / (float)cnt;
        } else {
            // fallback: top-MIN_KEPT via value bisection (exact enough; never
            // triggered with this data distribution, resolved on-device)
            float lo = 0.f, hi = 88.f;
            for (int it = 0; it < 40; ++it) {
                const float mid = 0.5f * (lo + hi);
                int c = 0;
                for (int i = threadIdx.x; i < HW; i += 256)
                    c += (pixel_loss(preds, tgts, bb, i) > mid) ? 1 : 0;
                c = block_reduce_int(c, ibuf);
                if (c >= MIN_KEPT) lo = mid; else hi = mid;
                __syncthreads();
            }
            float ssum = 0.f;
            int sc = 0;
            for (int i = threadIdx.x; i < HW; i += 256) {
                const float l = pixel_loss(preds, tgts, bb, i);
                if (l > lo) { ssum += l; ++sc; }
            }
            ssum = block_reduce_f(ssum, fbuf);
            sc = block_reduce_int(sc, ibuf);
            const float kept = ssum + (float)(MIN_KEPT - sc) * lo;
            mean = kept / (float)MIN_KEPT;
        }
        total += mean;
        __syncthreads();
    }
    if (threadIdx.x == 0) out[0] = total / (float)BB;
}

extern "C" void kernel_launch(void* const* d_in, const int* in_sizes, int n_in,
                              void* d_out, int out_size, void* d_ws, size_t ws_size,
                              hipStream_t stream) {
    const float* preds = (const float*)d_in[0];
    const int* tgts = (const int*)d_in[1];
    float* out = (float*)d_out;

    float* sums = (float*)d_ws;                            // 8 floats @ 0
    int* counts = (int*)((char*)d_ws + 64);                // 8 ints   @ 64
    unsigned int* ticket = (unsigned int*)((char*)d_ws + 128);  // 1 u32 @ 128

    hipMemsetAsync(d_ws, 0, 192, stream);

    dim3 grid(NBLKX, BB);
    ohem_fused<<<grid, 256, 0, stream>>>(preds, tgts, sums, counts, ticket, out);
}

// Round 2
// 563.621 us; speedup vs baseline: 1.1139x; 1.1139x over previous
//
#include <hip/hip_runtime.h>

// OHEM loss, MI355X. B=8, C=19, H=512, W=1024.
// v3: async global_load_lds staging.
//   Diagnosis from r1: both prior kernels were latency-starved (VALUBusy 9%,
//   BW 1.0-1.8 TB/s, ~1.5 outstanding wave-loads/CU). Register-file load
//   destinations (19 float4) cap MLP. Fix: stage the 19-class tile into LDS
//   via the async DMA path (no VGPR held per outstanding load), then compute
//   from LDS. Lane l consumes exactly what its own wave staged -> no barrier,
//   just per-wave s_waitcnt vmcnt(0).
// Main path: n_over = count(loss > 0.7) >> MIN_KEPT, so kept_sum ==
// sum(loss where loss > 0.7); no sort. Fallback via last-block bisection.

#define BB 8
#define CC 19
#define HW (512 * 1024)
#define THRESH 0.7f
#define MIN_KEPT 10000
#define QHW (HW / 4)          // 131072 quads per batch
#define TILE 256              // quads per block (4 KB per class in LDS)
#define NBLKX (QHW / TILE)    // 512 blocks per batch
#define NBLK (NBLKX * BB)     // 4096 blocks total

// async 16 B/lane global->LDS (hardware DMA; dest = wave-uniform base + lane*16)
#define GLOAD_LDS16(g, l)                                                     \
    __builtin_amdgcn_global_load_lds(                                         \
        (const __attribute__((address_space(1))) void*)(g),                   \
        (__attribute__((address_space(3))) void*)(l), 16, 0, 0)

__device__ __forceinline__ float wave_reduce_f(float v) {
#pragma unroll
    for (int off = 32; off > 0; off >>= 1) v += __shfl_down(v, off, 64);
    return v;
}
__device__ __forceinline__ int wave_reduce_i(int v) {
#pragma unroll
    for (int off = 32; off > 0; off >>= 1) v += __shfl_down(v, off, 64);
    return v;
}

// ---------------- fallback helpers (never triggered with this data) ----------
__device__ float pixel_loss(const float* __restrict__ preds,
                            const int* __restrict__ tgts, int b, int i) {
    const float* p = preds + (size_t)b * CC * HW + i;
    const int t = tgts[(size_t)b * HW + i];
    float m = -1e30f, tv = 0.f;
#pragma unroll
    for (int c = 0; c < CC; ++c) {
        float v = p[(size_t)c * HW];
        m = fmaxf(m, v);
        tv = (c == t) ? v : tv;
    }
    float s = 0.f;
#pragma unroll
    for (int c = 0; c < CC; ++c) s += __expf(p[(size_t)c * HW] - m);
    return m - tv + __logf(s);
}

__device__ int block_reduce_int(int v, int* buf) {
    v = wave_reduce_i(v);
    const int wid = threadIdx.x >> 6, lane = threadIdx.x & 63;
    __syncthreads();
    if (lane == 0) buf[wid] = v;
    __syncthreads();
    return buf[0] + buf[1] + buf[2] + buf[3];
}
__device__ float block_reduce_f(float v, float* buf) {
    v = wave_reduce_f(v);
    const int wid = threadIdx.x >> 6, lane = threadIdx.x & 63;
    __syncthreads();
    if (lane == 0) buf[wid] = v;
    __syncthreads();
    return buf[0] + buf[1] + buf[2] + buf[3];
}

// ---------------- fused loss + finalize ----------------
// grid: (NBLKX, BB), block: 256. Each thread: 4 consecutive pixels (one quad).
__global__ __launch_bounds__(256) void ohem_fused(
    const float* __restrict__ preds, const int* __restrict__ tgts,
    float* __restrict__ sums, int* __restrict__ counts,
    unsigned int* __restrict__ ticket, float* __restrict__ out) {

    __shared__ float cls[CC * TILE * 4];   // 19 * 4 KB = 77824 B
    __shared__ float sbuf[4];
    __shared__ int cbuf[4];
    __shared__ int lastflag;

    const int b = blockIdx.y;
    const int seg = blockIdx.x;
    const int tid = threadIdx.x;
    const int qb = seg * TILE;             // first quad of this block's tile

    if (tid == 0) lastflag = 0;

    // per-lane global base for this thread's quad (floats)
    const float* pbase = preds + (size_t)b * CC * HW + (size_t)qb * 4 + tid * 4;

    // target quad -> regs (coalesced int4)
    const int4 t = ((const int4*)(tgts + (size_t)b * HW))[qb + tid];

    // stage all 19 classes via async DMA; zero VGPRs held per outstanding load.
    // LDS dest per wave: uniform base (c*4096 + wave*1024) + lane*16  -> legal.
#pragma unroll
    for (int c = 0; c < CC; ++c) {
        GLOAD_LDS16(pbase + (size_t)c * HW, &cls[c * (TILE * 4) + tid * 4]);
    }
    // each wave consumes only its own staged lanes -> per-wave wait, no barrier
    asm volatile("s_waitcnt vmcnt(0)" ::: "memory");
    __builtin_amdgcn_sched_barrier(0);

    const float4* lv = (const float4*)cls;   // [CC * TILE] float4s

    // pass 1: componentwise max over classes
    float4 m = lv[tid];
#pragma unroll
    for (int c = 1; c < CC; ++c) {
        const float4 a = lv[c * TILE + tid];
        m.x = fmaxf(m.x, a.x);
        m.y = fmaxf(m.y, a.y);
        m.z = fmaxf(m.z, a.z);
        m.w = fmaxf(m.w, a.w);
    }
    // pass 2: sum exp(a - m) + select logit[target]
    float4 s = {0.f, 0.f, 0.f, 0.f};
    float4 tv = {0.f, 0.f, 0.f, 0.f};
#pragma unroll
    for (int c = 0; c < CC; ++c) {
        const float4 a = lv[c * TILE + tid];
        s.x += __expf(a.x - m.x);
        s.y += __expf(a.y - m.y);
        s.z += __expf(a.z - m.z);
        s.w += __expf(a.w - m.w);
        tv.x = (t.x == c) ? a.x : tv.x;
        tv.y = (t.y == c) ? a.y : tv.y;
        tv.z = (t.z == c) ? a.z : tv.z;
        tv.w = (t.w == c) ? a.w : tv.w;
    }

    const float l0 = m.x - tv.x + __logf(s.x);
    const float l1 = m.y - tv.y + __logf(s.y);
    const float l2 = m.z - tv.z + __logf(s.z);
    const float l3 = m.w - tv.w + __logf(s.w);

    float sloc = 0.f;
    int cloc = 0;
    if (l0 > THRESH) { sloc += l0; ++cloc; }
    if (l1 > THRESH) { sloc += l1; ++cloc; }
    if (l2 > THRESH) { sloc += l2; ++cloc; }
    if (l3 > THRESH) { sloc += l3; ++cloc; }

    // block reduce: 4 waves
    const float wsum = wave_reduce_f(sloc);
    const int wcnt = wave_reduce_i(cloc);
    const int wid = threadIdx.x >> 6;
    const int lane = threadIdx.x & 63;
    if (lane == 0) { sbuf[wid] = wsum; cbuf[wid] = wcnt; }
    __syncthreads();
    if (threadIdx.x == 0) {
        const float st = sbuf[0] + sbuf[1] + sbuf[2] + sbuf[3];
        const int ct = cbuf[0] + cbuf[1] + cbuf[2] + cbuf[3];
        atomicAdd(&sums[b], st);
        atomicAdd(&counts[b], ct);
        __threadfence();  // make our adds visible before taking a ticket
        const unsigned int old = atomicAdd(ticket, 1u);
        if (old == (unsigned int)(NBLK - 1)) lastflag = 1;
    }
    __syncthreads();
    if (!lastflag) return;

    // ---- last block: finalize ----
    __shared__ int ibuf[4];
    __shared__ float fbuf[4];
    __shared__ float s_sm;
    __shared__ int s_ct;

    float total = 0.f;
    for (int bb = 0; bb < BB; ++bb) {
        if (threadIdx.x == 0) {
            // device-scope atomic reads (avoid stale L1/L2 copies)
            s_sm = atomicAdd(&sums[bb], 0.0f);
            s_ct = atomicAdd(&counts[bb], 0);
        }
        __syncthreads();
        const int cnt = s_ct;
        const float sm = s_sm;
        float mean;
        if (cnt >= MIN_KEPT) {
            // top-n_over == exactly the losses > THRESH
            mean = sm / (float)cnt;
        } else {
            // fallback: top-MIN_KEPT via value bisection (never triggered with
            // this data distribution; resolved on-device)
            float lo = 0.f, hi = 88.f;
            for (int it = 0; it < 40; ++it) {
                const float mid = 0.5f * (lo + hi);
                int c = 0;
                for (int i = threadIdx.x; i < HW; i += 256)
                    c += (pixel_loss(preds, tgts, bb, i) > mid) ? 1 : 0;
                c = block_reduce_int(c, ibuf);
                if (c >= MIN_KEPT) lo = mid; else hi = mid;
                __syncthreads();
            }
            float ssum = 0.f;
            int sc = 0;
            for (int i = threadIdx.x; i < HW; i += 256) {
                const float l = pixel_loss(preds, tgts, bb, i);
                if (l > lo) { ssum += l; ++sc; }
            }
            ssum = block_reduce_f(ssum, fbuf);
            sc = block_reduce_int(sc, ibuf);
            const float kept = ssum + (float)(MIN_KEPT - sc) * lo;
            mean = kept / (float)MIN_KEPT;
        }
        total += mean;
        __syncthreads();
    }
    if (threadIdx.x == 0) out[0] = total / (float)BB;
}

extern "C" void kernel_launch(void* const* d_in, const int* in_sizes, int n_in,
                              void* d_out, int out_size, void* d_ws, size_t ws_size,
                              hipStream_t stream) {
    const float* preds = (const float*)d_in[0];
    const int* tgts = (const int*)d_in[1];
    float* out = (float*)d_out;

    float* sums = (float*)d_ws;                                 // 8 floats @ 0
    int* counts = (int*)((char*)d_ws + 64);                     // 8 ints   @ 64
    unsigned int* ticket = (unsigned int*)((char*)d_ws + 128);  // 1 u32    @ 128

    hipMemsetAsync(d_ws, 0, 192, stream);

    dim3 grid(NBLKX, BB);
    ohem_fused<<<grid, 256, 0, stream>>>(preds, tgts, sums, counts, ticket, out);
}

// Round 4
// 432.834 us; speedup vs baseline: 1.4505x; 1.3022x over previous
//
#include <hip/hip_runtime.h>

// OHEM loss, MI355X. B=8, C=19, H=512, W=1024.
// v5 = v4 with launch-safety fixes (r3 container died with no counters):
//   - LDS 155648 B (was 163840 == exact 160 KiB limit): targets moved out of
//     LDS-DMA into register prefetch via a 2x-unrolled pipeline (tA/tB), so
//     each target read is one full tile behind its load and the compiler's
//     own waitcnt matches our counted vmcnt(20).
//   - otherwise identical: 256 persistent blocks (1/CU), double-buffered
//     global_load_lds staging, COUNTED s_waitcnt vmcnt(20) (never 0 in the
//     steady state), per-wave self-consumption -> zero barriers in the loop,
//     one atomic pair per block, separate tiny finalize kernel.
// Main path: n_over = count(loss > 0.7) >> MIN_KEPT, so kept_sum ==
// sum(loss where loss > 0.7); no sort. Fallback via bisection in finalize.

#define BB 8
#define CC 19
#define HW (512 * 1024)
#define THRESH 0.7f
#define MIN_KEPT 10000
#define QHW (HW / 4)           // 131072 quads per batch
#define TILE 256               // quads per tile (one per thread)
#define SEGS (QHW / TILE)      // 512 tiles per batch
#define NTILE (SEGS * BB)      // 4096 tiles total
#define NPBLK 256              // persistent blocks (1 per CU)
#define TPB (NTILE / NPBLK)    // 16 tiles per block (16 | 512 -> same batch)

#define BUFF 19456             // floats per LDS buffer (19 * 4 KB = 77824 B)

// async 16 B/lane global->LDS DMA (dest = wave-uniform base + lane*16)
#define GLOAD_LDS16(g, l)                                                     \
    __builtin_amdgcn_global_load_lds(                                         \
        (const __attribute__((address_space(1))) void*)(g),                   \
        (__attribute__((address_space(3))) void*)(l), 16, 0, 0)

__device__ __forceinline__ float wave_reduce_f(float v) {
#pragma unroll
    for (int off = 32; off > 0; off >>= 1) v += __shfl_down(v, off, 64);
    return v;
}
__device__ __forceinline__ int wave_reduce_i(int v) {
#pragma unroll
    for (int off = 32; off > 0; off >>= 1) v += __shfl_down(v, off, 64);
    return v;
}

// stage one tile's 19 class rows into an LDS buffer via async DMA
__device__ __forceinline__ void stage19(const float* pb, int seg, float* lbuf,
                                        int tid) {
    const float* gp = pb + (size_t)seg * (TILE * 4) + tid * 4;
#pragma unroll
    for (int c = 0; c < CC; ++c) {
        GLOAD_LDS16(gp + (size_t)c * HW, lbuf + c * (TILE * 4) + tid * 4);
    }
}

// compute one tile from an LDS buffer; accumulate kept sum/count
__device__ __forceinline__ void tile_compute(const float* base, int4 t, int tid,
                                             float& sloc, int& cloc) {
    const float4* lv = (const float4*)base;
    // pass 1: componentwise max over classes
    float4 m = lv[tid];
#pragma unroll
    for (int c = 1; c < CC; ++c) {
        const float4 a = lv[c * TILE + tid];
        m.x = fmaxf(m.x, a.x);
        m.y = fmaxf(m.y, a.y);
        m.z = fmaxf(m.z, a.z);
        m.w = fmaxf(m.w, a.w);
    }
    // pass 2: sum exp(a - m) + select logit[target]
    float4 s = {0.f, 0.f, 0.f, 0.f};
    float4 tv = {0.f, 0.f, 0.f, 0.f};
#pragma unroll
    for (int c = 0; c < CC; ++c) {
        const float4 a = lv[c * TILE + tid];
        s.x += __expf(a.x - m.x);
        s.y += __expf(a.y - m.y);
        s.z += __expf(a.z - m.z);
        s.w += __expf(a.w - m.w);
        tv.x = (t.x == c) ? a.x : tv.x;
        tv.y = (t.y == c) ? a.y : tv.y;
        tv.z = (t.z == c) ? a.z : tv.z;
        tv.w = (t.w == c) ? a.w : tv.w;
    }
    const float l0 = m.x - tv.x + __logf(s.x);
    const float l1 = m.y - tv.y + __logf(s.y);
    const float l2 = m.z - tv.z + __logf(s.z);
    const float l3 = m.w - tv.w + __logf(s.w);
    if (l0 > THRESH) { sloc += l0; ++cloc; }
    if (l1 > THRESH) { sloc += l1; ++cloc; }
    if (l2 > THRESH) { sloc += l2; ++cloc; }
    if (l3 > THRESH) { sloc += l3; ++cloc; }
}

// ---------------- main: persistent pipelined loss pass ----------------
__global__ __launch_bounds__(256) void ohem_main(
    const float* __restrict__ preds, const int* __restrict__ tgts,
    float* __restrict__ sums, int* __restrict__ counts) {

    __shared__ float cls[2 * BUFF];   // 155648 B (8 KB under the 160 KiB cap)
    __shared__ float sbuf[4];
    __shared__ int cbuf[4];

    const int tid = threadIdx.x;
    const int g0 = blockIdx.x * TPB;       // first tile of this block
    const int b = g0 / SEGS;               // batch (constant per block)
    const int seg0 = g0 % SEGS;

    const float* pb = preds + (size_t)b * CC * HW;
    const int4* tq = (const int4*)(tgts + (size_t)b * HW);

    // prologue: stage tile 0 into buf0, prefetch its targets (20 vmem total)
    stage19(pb, seg0, cls, tid);
    int4 tA = tq[(size_t)seg0 * TILE + tid];
    int4 tB;

    float sloc = 0.f;
    int cloc = 0;

#pragma unroll 1
    for (int i = 0; i < TPB; i += 2) {
        // ---- even sub-iter: tile i from buf0 (targets tA) ----
        // issue tile i+1's 20-op group, then wait only for tile i's 20
        stage19(pb, seg0 + i + 1, cls + BUFF, tid);
        tB = tq[(size_t)(seg0 + i + 1) * TILE + tid];
        asm volatile("s_waitcnt vmcnt(20)" ::: "memory");
        __builtin_amdgcn_sched_barrier(0);
        tile_compute(cls, tA, tid, sloc, cloc);

        // ---- odd sub-iter: tile i+1 from buf1 (targets tB) ----
        if (i + 2 < TPB) {
            stage19(pb, seg0 + i + 2, cls, tid);
            tA = tq[(size_t)(seg0 + i + 2) * TILE + tid];
            asm volatile("s_waitcnt vmcnt(20)" ::: "memory");
        } else {
            asm volatile("s_waitcnt vmcnt(0)" ::: "memory");
        }
        __builtin_amdgcn_sched_barrier(0);
        tile_compute(cls + BUFF, tB, tid, sloc, cloc);
    }

    // block reduce -> one atomic pair per block
    const float wsum = wave_reduce_f(sloc);
    const int wcnt = wave_reduce_i(cloc);
    const int wid = tid >> 6;
    const int lane = tid & 63;
    if (lane == 0) { sbuf[wid] = wsum; cbuf[wid] = wcnt; }
    __syncthreads();
    if (tid == 0) {
        atomicAdd(&sums[b], sbuf[0] + sbuf[1] + sbuf[2] + sbuf[3]);
        atomicAdd(&counts[b], cbuf[0] + cbuf[1] + cbuf[2] + cbuf[3]);
    }
}

// ---------------- finalize (1 block; fallback never triggered) --------------
__device__ float pixel_loss(const float* __restrict__ preds,
                            const int* __restrict__ tgts, int b, int i) {
    const float* p = preds + (size_t)b * CC * HW + i;
    const int t = tgts[(size_t)b * HW + i];
    float m = -1e30f, tv = 0.f;
#pragma unroll
    for (int c = 0; c < CC; ++c) {
        float v = p[(size_t)c * HW];
        m = fmaxf(m, v);
        tv = (c == t) ? v : tv;
    }
    float s = 0.f;
#pragma unroll
    for (int c = 0; c < CC; ++c) s += __expf(p[(size_t)c * HW] - m);
    return m - tv + __logf(s);
}

__device__ int block_reduce_int(int v, int* buf) {
    v = wave_reduce_i(v);
    const int wid = threadIdx.x >> 6, lane = threadIdx.x & 63;
    __syncthreads();
    if (lane == 0) buf[wid] = v;
    __syncthreads();
    return buf[0] + buf[1] + buf[2] + buf[3];
}
__device__ float block_reduce_f(float v, float* buf) {
    v = wave_reduce_f(v);
    const int wid = threadIdx.x >> 6, lane = threadIdx.x & 63;
    __syncthreads();
    if (lane == 0) buf[wid] = v;
    __syncthreads();
    return buf[0] + buf[1] + buf[2] + buf[3];
}

__global__ __launch_bounds__(256) void ohem_finalize(
    const float* __restrict__ preds, const int* __restrict__ tgts,
    const float* __restrict__ sums, const int* __restrict__ counts,
    float* __restrict__ out) {
    __shared__ int ibuf[4];
    __shared__ float fbuf[4];

    float total = 0.f;
    for (int b = 0; b < BB; ++b) {
        const int cnt = counts[b];
        const float sm = sums[b];
        float mean;
        if (cnt >= MIN_KEPT) {
            mean = sm / (float)cnt;   // top-n_over == exactly losses > THRESH
        } else {
            // fallback: top-MIN_KEPT via value bisection
            float lo = 0.f, hi = 88.f;
            for (int it = 0; it < 40; ++it) {
                const float mid = 0.5f * (lo + hi);
                int c = 0;
                for (int i = threadIdx.x; i < HW; i += 256)
                    c += (pixel_loss(preds, tgts, b, i) > mid) ? 1 : 0;
                c = block_reduce_int(c, ibuf);
                if (c >= MIN_KEPT) lo = mid; else hi = mid;
                __syncthreads();
            }
            float ssum = 0.f;
            int sc = 0;
            for (int i = threadIdx.x; i < HW; i += 256) {
                const float l = pixel_loss(preds, tgts, b, i);
                if (l > lo) { ssum += l; ++sc; }
            }
            ssum = block_reduce_f(ssum, fbuf);
            sc = block_reduce_int(sc, ibuf);
            const float kept = ssum + (float)(MIN_KEPT - sc) * lo;
            mean = kept / (float)MIN_KEPT;
        }
        total += mean;
        __syncthreads();
    }
    if (threadIdx.x == 0) out[0] = total / (float)BB;
}

extern "C" void kernel_launch(void* const* d_in, const int* in_sizes, int n_in,
                              void* d_out, int out_size, void* d_ws, size_t ws_size,
                              hipStream_t stream) {
    const float* preds = (const float*)d_in[0];
    const int* tgts = (const int*)d_in[1];
    float* out = (float*)d_out;

    float* sums = (float*)d_ws;               // 8 floats @ 0
    int* counts = (int*)((char*)d_ws + 64);   // 8 ints   @ 64

    hipMemsetAsync(d_ws, 0, 128, stream);

    ohem_main<<<dim3(NPBLK), 256, 0, stream>>>(preds, tgts, sums, counts);
    ohem_finalize<<<1, 256, 0, stream>>>(preds, tgts, sums, counts, out);
}